// Round 8
// baseline (211.831 us; speedup 1.0000x reference)
//
#include <hip/hip_runtime.h>

// SRM neuron: per-row 50-tap 'same' conv -> threshold -> refractory scan.
// B=4096 rows, T=16384.
// R8: decouple conv from the (rare) refractory repair.
//   K1: 2 chunks/row (8192 waves), conv via wave-private LDS tile, exact
//       threshold compare, spikes := cand stored directly; per-chunk flag
//       (any candidate) into d_ws. No scan in the hot loop.
//   K2: wave/row; rows with any flag re-read their cand row, run the exact
//       transfer-map refractory scan, rewrite. Rows w/o candidates exit.
//   Exact for any input (K2 repairs every flagged row).
// Fallback: validated R7 single kernel if ws too small.

#define TLEN  16384
#define NROWS 4096
#define GRP   256     // elements per group (64 lanes x 4)
#define NGRP  64      // groups per row
#define KLEN  50
#define WPB   4       // waves per 256-thread block
#define TILEW 336     // padded tile stride (floats); 16B-aligned
#define CHK   2       // chunks per row (K1)
#define GPC   (NGRP / CHK)   // 32 groups per chunk

#define WS_NEED ((size_t)NROWS * CHK * sizeof(int))   // 32 KB of flags

typedef float f4 __attribute__((ext_vector_type(4)));

__device__ __forceinline__ float uniformf(float x) {
    return __int_as_float(__builtin_amdgcn_readfirstlane(__float_as_int(x)));
}

// compose: r[s] = then[first[s]]  (apply `first`, then `then`)
__device__ __forceinline__ int map_compose(int first, int then) {
    int r = 0;
#pragma unroll
    for (int s = 0; s < 4; ++s) {
        int a = (first >> (2 * s)) & 3;
        int b = (then >> (2 * a)) & 3;
        r |= b << (2 * s);
    }
    return r;
}

// Smallest float a with (v_reset + a/100.0f) >= v_th, via exact-predicate
// binary search over order-mapped float bits. cand == (acc >= athr) EXACTLY.
__device__ float solve_thresh(float v_reset, float v_th) {
    auto tokey = [](float f) {
        unsigned u = __float_as_uint(f);
        return (u & 0x80000000u) ? ~u : (u | 0x80000000u);
    };
    auto fromkey = [](unsigned k) {
        unsigned u = (k & 0x80000000u) ? (k & 0x7FFFFFFFu) : ~k;
        return __uint_as_float(u);
    };
    const float maxf = 3.402823466e38f;
    unsigned lo = tokey(-maxf), hi = tokey(maxf);
    if (!((v_reset + maxf / 100.0f) >= v_th))
        return __uint_as_float(0x7F800000u);  // pred never true -> +inf
    while (lo < hi) {
        unsigned mid = lo + ((hi - lo) >> 1);
        float a = fromkey(mid);
        if ((v_reset + a / 100.0f) >= v_th) hi = mid;
        else lo = mid + 1;
    }
    return fromkey(lo);
}

// ---------------- K1: conv -> spikes(=cand) + per-chunk flags ----------------
__global__ __launch_bounds__(256)
void conv_kernel(const float* __restrict__ I,
                 const float* __restrict__ p_tau_m,
                 const float* __restrict__ p_tau_s,
                 const float* __restrict__ p_v_th,
                 const float* __restrict__ p_v_reset,
                 float* __restrict__ out,
                 int* __restrict__ flags)
{
    __shared__ __align__(16) float tile[WPB][2][TILEW];

    const int lane  = threadIdx.x & 63;
    const int wid   = threadIdx.x >> 6;
    const int w     = blockIdx.x * WPB + wid;    // 0 .. NROWS*CHK-1
    const int row   = w >> 1;
    const int chunk = w & 1;
    const int gi0   = chunk * GPC;

    const float tau_m   = p_tau_m[0];
    const float tau_s   = p_tau_s[0];
    const float v_th    = p_v_th[0];
    const float v_reset = p_v_reset[0];

    // Taps pinned wave-uniform (validated bit-exact R1-R7).
    float ku[KLEN];
    float ksum = 0.0f;
#pragma unroll
    for (int t = 0; t < KLEN; ++t) {
        float ft = (float)t;
        float v = expf(-ft / tau_m) - expf(-ft / tau_s);
        ksum += v;
        ku[t] = uniformf(v);
    }
    const float kden = uniformf(ksum + 1e-10f);
    float kt[KLEN];
#pragma unroll
    for (int t = 0; t < KLEN; ++t) kt[t] = uniformf(ku[t] / kden);

    const float athr = uniformf(solve_thresh(v_reset, v_th));

    const float* Irow = I + (size_t)row * TLEN;
    float* Orow = out + (size_t)row * TLEN;

    float Cv[4], Nv[4], Lv[4];
    {
        f4 a = *(const f4*)(Irow + (size_t)gi0 * GRP + 4 * lane);
        Cv[0] = a.x; Cv[1] = a.y; Cv[2] = a.z; Cv[3] = a.w;
        f4 c = *(const f4*)(Irow + (size_t)(gi0 + 1) * GRP + 4 * lane);
        Nv[0] = c.x; Nv[1] = c.y; Nv[2] = c.z; Nv[3] = c.w;
    }

    // Prologue tile0: halo-left (zeros for row start, else real data), main.
    if (lane < 8) {
        f4 h;
        if (chunk == 0) h = (f4){0.0f, 0.0f, 0.0f, 0.0f};
        else            h = *(const f4*)(Irow + (size_t)gi0 * GRP - 32 + 4 * lane);
        *(f4*)&tile[wid][0][4 * lane] = h;
    }
    {
        f4 c; c.x = Cv[0]; c.y = Cv[1]; c.z = Cv[2]; c.w = Cv[3];
        *(f4*)&tile[wid][0][32 + 4 * lane] = c;
    }

    int rowflag = 0;

    for (int g = 0; g < GPC; ++g) {
        const int cur = g & 1;
        const int nxt = cur ^ 1;
        const int gi  = gi0 + g;

        // ---- prefetch group gi+2 (real data across chunk bound; zeros past row) ----
        if (gi + 2 < NGRP) {
            f4 a = __builtin_nontemporal_load(
                (const f4*)(Irow + (size_t)(gi + 2) * GRP + 4 * lane));
            Lv[0] = a.x; Lv[1] = a.y; Lv[2] = a.z; Lv[3] = a.w;
        } else {
            Lv[0] = Lv[1] = Lv[2] = Lv[3] = 0.0f;
        }

        // ---- tile maintenance (wave-private LDS, same-wave in-order) ----
        f4 nv; nv.x = Nv[0]; nv.y = Nv[1]; nv.z = Nv[2]; nv.w = Nv[3];
        if (lane < 8)
            *(f4*)&tile[wid][cur][288 + 4 * lane] = nv;
        *(f4*)&tile[wid][nxt][32 + 4 * lane] = nv;
        if (lane >= 56) {
            f4 cv; cv.x = Cv[0]; cv.y = Cv[1]; cv.z = Cv[2]; cv.w = Cv[3];
            *(f4*)&tile[wid][nxt][4 * (lane - 56)] = cv;
        }

        // ---- window read: elems 4l+4 .. 4l+63 ----
        f4 wv[15];
#pragma unroll
        for (int i = 0; i < 15; ++i)
            wv[i] = *(const f4*)&tile[wid][cur][4 * lane + 4 + 4 * i];
#define WIN(m) (wv[(m) >> 2][(m) & 3])

        // ---- convolution: identical order/operands to R6/R7 ----
        float acc[4];
        acc[0] = acc[1] = acc[2] = acc[3] = 0.0f;
#pragma unroll
        for (int o = -25; o <= 27; ++o) {
            const float w2 = WIN(o + 28);
#pragma unroll
            for (int k = 0; k < 4; ++k) {
                const int jj = k + 24 - o;
                if (jj >= 0 && jj < KLEN)
                    acc[k] = fmaf(kt[jj], w2, acc[k]);
            }
        }
#undef WIN

        // ---- candidates -> spikes (repair of refractory overlaps in K2) ----
        const int tb = gi * GRP + 4 * lane;
        int cand[4];
#pragma unroll
        for (int k = 0; k < 4; ++k)
            cand[k] = (acc[k] >= athr) ? 1 : 0;
        cand[0] &= (tb != 0);   // spikes[0] forced 0

        rowflag |= cand[0] | cand[1] | cand[2] | cand[3];

        f4 o0;
        o0.x = cand[0] ? 1.0f : 0.0f;
        o0.y = cand[1] ? 1.0f : 0.0f;
        o0.z = cand[2] ? 1.0f : 0.0f;
        o0.w = cand[3] ? 1.0f : 0.0f;
        __builtin_nontemporal_store(o0, (f4*)(Orow + tb));

        // ---- rotate ----
#pragma unroll
        for (int j = 0; j < 4; ++j) { Cv[j] = Nv[j]; Nv[j] = Lv[j]; }
    }

    // Deterministic flag write for every chunk (0 or 1).
    const unsigned long long anyb = __ballot(rowflag != 0);
    if (lane == 0) flags[w] = (anyb != 0ULL) ? 1 : 0;
}

// ---------------- K2: repair flagged rows with exact refractory scan ----------------
__global__ __launch_bounds__(256)
void fixup_kernel(const int* __restrict__ flags,
                  float* __restrict__ out)
{
    const int lane = threadIdx.x & 63;
    const int wid  = threadIdx.x >> 6;
    const int row  = blockIdx.x * WPB + wid;

    if ((flags[2 * row] | flags[2 * row + 1]) == 0) return;  // wave-uniform

    float* Orow = out + (size_t)row * TLEN;
    int r0 = 0;

    for (int g = 0; g < NGRP; ++g) {
        f4 o = *(const f4*)(Orow + g * GRP + 4 * lane);
        int cand[4];
        cand[0] = (o.x != 0.0f);
        cand[1] = (o.y != 0.0f);
        cand[2] = (o.z != 0.0f);
        cand[3] = (o.w != 0.0f);

        const int cm = cand[0] | cand[1] | cand[2] | cand[3];
        const unsigned long long anyc = __ballot(cm != 0);
        if (anyc == 0ULL) { r0 = 0; continue; }   // zeros already correct

        // ---- per-lane 4-step transfer map ----
        int s0 = 0, s1 = 1, s2 = 2, s3 = 3;
#pragma unroll
        for (int k = 0; k < 4; ++k) {
            const int c3 = cand[k] ? 3 : 0;
            s0 = (s0 > 0) ? (s0 - 1) : c3;
            s1 = (s1 > 0) ? (s1 - 1) : c3;
            s2 = (s2 > 0) ? (s2 - 1) : c3;
            s3 = (s3 > 0) ? (s3 - 1) : c3;
        }
        int P = s0 | (s1 << 2) | (s2 << 4) | (s3 << 6);

        // ---- inclusive prefix composition across 64 lanes ----
#pragma unroll
        for (int d = 1; d < 64; d <<= 1) {
            const int prev = __shfl_up(P, d, 64);
            const int comp = map_compose(prev, P);
            P = (lane >= d) ? comp : P;
        }
        const int Pprev = __shfl_up(P, 1, 64);
        const int sin0  = (lane == 0) ? r0 : ((Pprev >> (2 * r0)) & 3);
        const int Pfull = __shfl(P, 63, 64);
        r0 = (Pfull >> (2 * r0)) & 3;

        // ---- replay and rewrite ----
        int s = sin0;
        float sp[4];
#pragma unroll
        for (int k = 0; k < 4; ++k) {
            const int spike = (s == 0) & cand[k];
            sp[k] = spike ? 1.0f : 0.0f;
            s = (s > 0) ? (s - 1) : (cand[k] ? 3 : 0);
        }
        f4 o0; o0.x = sp[0]; o0.y = sp[1]; o0.z = sp[2]; o0.w = sp[3];
        *(f4*)(Orow + g * GRP + 4 * lane) = o0;
    }
}

// ---------------- Fallback: validated R7 single kernel ----------------
__global__ __launch_bounds__(256)
void srm_kernel(const float* __restrict__ I,
                const float* __restrict__ p_tau_m,
                const float* __restrict__ p_tau_s,
                const float* __restrict__ p_v_th,
                const float* __restrict__ p_v_reset,
                float* __restrict__ out)
{
    __shared__ __align__(16) float tile[WPB][2][TILEW];

    const int lane = threadIdx.x & 63;
    const int wid  = threadIdx.x >> 6;
    const int row  = blockIdx.x * WPB + wid;

    const float tau_m   = p_tau_m[0];
    const float tau_s   = p_tau_s[0];
    const float v_th    = p_v_th[0];
    const float v_reset = p_v_reset[0];

    float ku[KLEN];
    float ksum = 0.0f;
#pragma unroll
    for (int t = 0; t < KLEN; ++t) {
        float ft = (float)t;
        float v = expf(-ft / tau_m) - expf(-ft / tau_s);
        ksum += v;
        ku[t] = uniformf(v);
    }
    const float kden = uniformf(ksum + 1e-10f);
    float kt[KLEN];
#pragma unroll
    for (int t = 0; t < KLEN; ++t) kt[t] = uniformf(ku[t] / kden);

    const float athr = uniformf(solve_thresh(v_reset, v_th));

    const float* Irow = I + (size_t)row * TLEN;
    float* Orow = out + (size_t)row * TLEN;

    float Cv[4], Nv[4], Lv[4];
    {
        f4 a = *(const f4*)(Irow + 0 * GRP + 4 * lane);
        Cv[0] = a.x; Cv[1] = a.y; Cv[2] = a.z; Cv[3] = a.w;
        f4 c = *(const f4*)(Irow + 1 * GRP + 4 * lane);
        Nv[0] = c.x; Nv[1] = c.y; Nv[2] = c.z; Nv[3] = c.w;
    }

    if (lane < 8) {
        f4 z = (f4){0.0f, 0.0f, 0.0f, 0.0f};
        *(f4*)&tile[wid][0][4 * lane] = z;
    }
    {
        f4 c; c.x = Cv[0]; c.y = Cv[1]; c.z = Cv[2]; c.w = Cv[3];
        *(f4*)&tile[wid][0][32 + 4 * lane] = c;
    }

    int r0 = 0;

    for (int g = 0; g < NGRP; ++g) {
        const int cur = g & 1;
        const int nxt = cur ^ 1;

        if (g + 2 < NGRP) {
            f4 a = __builtin_nontemporal_load(
                (const f4*)(Irow + (size_t)(g + 2) * GRP + 4 * lane));
            Lv[0] = a.x; Lv[1] = a.y; Lv[2] = a.z; Lv[3] = a.w;
        } else {
            Lv[0] = Lv[1] = Lv[2] = Lv[3] = 0.0f;
        }

        f4 nv; nv.x = Nv[0]; nv.y = Nv[1]; nv.z = Nv[2]; nv.w = Nv[3];
        if (lane < 8)
            *(f4*)&tile[wid][cur][288 + 4 * lane] = nv;
        *(f4*)&tile[wid][nxt][32 + 4 * lane] = nv;
        if (lane >= 56) {
            f4 cv; cv.x = Cv[0]; cv.y = Cv[1]; cv.z = Cv[2]; cv.w = Cv[3];
            *(f4*)&tile[wid][nxt][4 * (lane - 56)] = cv;
        }

        f4 wv[15];
#pragma unroll
        for (int i = 0; i < 15; ++i)
            wv[i] = *(const f4*)&tile[wid][cur][4 * lane + 4 + 4 * i];
#define WIN(m) (wv[(m) >> 2][(m) & 3])

        float acc[4];
        acc[0] = acc[1] = acc[2] = acc[3] = 0.0f;
#pragma unroll
        for (int o = -25; o <= 27; ++o) {
            const float w = WIN(o + 28);
#pragma unroll
            for (int k = 0; k < 4; ++k) {
                const int jj = k + 24 - o;
                if (jj >= 0 && jj < KLEN)
                    acc[k] = fmaf(kt[jj], w, acc[k]);
            }
        }
#undef WIN

        const int tb = g * GRP + 4 * lane;
        int cand[4];
#pragma unroll
        for (int k = 0; k < 4; ++k)
            cand[k] = (acc[k] >= athr) ? 1 : 0;
        cand[0] &= (tb != 0);

        const int cm = cand[0] | cand[1] | cand[2] | cand[3];
        const unsigned long long anyc = __ballot(cm != 0);

        f4 o0;
        if (anyc == 0ULL) {
            o0 = (f4){0.0f, 0.0f, 0.0f, 0.0f};
            r0 = 0;
        } else {
            int s0 = 0, s1 = 1, s2 = 2, s3 = 3;
#pragma unroll
            for (int k = 0; k < 4; ++k) {
                const int c3 = cand[k] ? 3 : 0;
                s0 = (s0 > 0) ? (s0 - 1) : c3;
                s1 = (s1 > 0) ? (s1 - 1) : c3;
                s2 = (s2 > 0) ? (s2 - 1) : c3;
                s3 = (s3 > 0) ? (s3 - 1) : c3;
            }
            int P = s0 | (s1 << 2) | (s2 << 4) | (s3 << 6);
#pragma unroll
            for (int d = 1; d < 64; d <<= 1) {
                const int prev = __shfl_up(P, d, 64);
                const int comp = map_compose(prev, P);
                P = (lane >= d) ? comp : P;
            }
            const int Pprev = __shfl_up(P, 1, 64);
            const int sin0  = (lane == 0) ? r0 : ((Pprev >> (2 * r0)) & 3);
            const int Pfull = __shfl(P, 63, 64);
            r0 = (Pfull >> (2 * r0)) & 3;

            int s = sin0;
            float sp[4];
#pragma unroll
            for (int k = 0; k < 4; ++k) {
                const int spike = (s == 0) & cand[k];
                sp[k] = spike ? 1.0f : 0.0f;
                s = (s > 0) ? (s - 1) : (cand[k] ? 3 : 0);
            }
            o0.x = sp[0]; o0.y = sp[1]; o0.z = sp[2]; o0.w = sp[3];
        }

        __builtin_nontemporal_store(o0, (f4*)(Orow + tb));

#pragma unroll
        for (int j = 0; j < 4; ++j) { Cv[j] = Nv[j]; Nv[j] = Lv[j]; }
    }
}

extern "C" void kernel_launch(void* const* d_in, const int* in_sizes, int n_in,
                              void* d_out, int out_size, void* d_ws, size_t ws_size,
                              hipStream_t stream) {
    const float* I       = (const float*)d_in[0];
    const float* tau_m   = (const float*)d_in[1];
    const float* tau_s   = (const float*)d_in[2];
    const float* v_th    = (const float*)d_in[3];
    const float* v_reset = (const float*)d_in[4];
    float* out = (float*)d_out;

    if (ws_size >= WS_NEED) {
        int* flags = (int*)d_ws;
        conv_kernel<<<dim3(NROWS * CHK / WPB), dim3(256), 0, stream>>>(
            I, tau_m, tau_s, v_th, v_reset, out, flags);
        fixup_kernel<<<dim3(NROWS / WPB), dim3(256), 0, stream>>>(flags, out);
    } else {
        srm_kernel<<<dim3(NROWS / WPB), dim3(256), 0, stream>>>(
            I, tau_m, tau_s, v_th, v_reset, out);
    }
}

// Round 9
// 182.139 us; speedup vs baseline: 1.1630x; 1.1630x over previous
//
#include <hip/hip_runtime.h>

// SRM neuron: per-row 50-tap 'same' conv -> threshold -> refractory scan.
// B=4096 rows, T=16384.
// R9: hoist per-wave setup (100 expf + 50 IEEE divs + 32-step binary search
//     ~= 30k cycles/wave, 41% of R7's VALU time) into a one-workgroup K0
//     that writes taps+athr to d_ws. Conv waves s_load them.
//   K0: taps (bit-identical, reference-ordered sum) + exact threshold.
//   K1: chunked conv (2 chunks/row, 8192 waves), LDS window tile,
//       spikes := cand, per-chunk flags. No transcendentals.
//   K2: repair flagged rows with the exact transfer-map refractory scan.
// Fallback: validated self-contained R7 kernel if ws too small.

#define TLEN  16384
#define NROWS 4096
#define GRP   256     // elements per group (64 lanes x 4)
#define NGRP  64      // groups per row
#define KLEN  50
#define WPB   4       // waves per 256-thread block
#define TILEW 336     // padded tile stride (floats); 16B-aligned
#define CHK   2       // chunks per row (K1)
#define GPC   (NGRP / CHK)   // 32 groups per chunk

// d_ws layout: float[0..49] taps, float[50] athr, flags int[] at byte 256.
#define WS_FLAGS_OFF 256
#define WS_NEED (WS_FLAGS_OFF + (size_t)NROWS * CHK * sizeof(int))

typedef float f4 __attribute__((ext_vector_type(4)));

__device__ __forceinline__ float uniformf(float x) {
    return __int_as_float(__builtin_amdgcn_readfirstlane(__float_as_int(x)));
}

// compose: r[s] = then[first[s]]  (apply `first`, then `then`)
__device__ __forceinline__ int map_compose(int first, int then) {
    int r = 0;
#pragma unroll
    for (int s = 0; s < 4; ++s) {
        int a = (first >> (2 * s)) & 3;
        int b = (then >> (2 * a)) & 3;
        r |= b << (2 * s);
    }
    return r;
}

// Smallest float a with (v_reset + a/100.0f) >= v_th, via exact-predicate
// binary search over order-mapped float bits. cand == (acc >= athr) EXACTLY.
__device__ float solve_thresh(float v_reset, float v_th) {
    auto tokey = [](float f) {
        unsigned u = __float_as_uint(f);
        return (u & 0x80000000u) ? ~u : (u | 0x80000000u);
    };
    auto fromkey = [](unsigned k) {
        unsigned u = (k & 0x80000000u) ? (k & 0x7FFFFFFFu) : ~k;
        return __uint_as_float(u);
    };
    const float maxf = 3.402823466e38f;
    unsigned lo = tokey(-maxf), hi = tokey(maxf);
    if (!((v_reset + maxf / 100.0f) >= v_th))
        return __uint_as_float(0x7F800000u);  // pred never true -> +inf
    while (lo < hi) {
        unsigned mid = lo + ((hi - lo) >> 1);
        float a = fromkey(mid);
        if ((v_reset + a / 100.0f) >= v_th) hi = mid;
        else lo = mid + 1;
    }
    return fromkey(lo);
}

// ---------------- K0: taps + exact threshold -> d_ws ----------------
__global__ __launch_bounds__(64)
void setup_kernel(const float* __restrict__ p_tau_m,
                  const float* __restrict__ p_tau_s,
                  const float* __restrict__ p_v_th,
                  const float* __restrict__ p_v_reset,
                  float* __restrict__ wsf)
{
    const int lane = threadIdx.x & 63;
    const float tau_m   = p_tau_m[0];
    const float tau_s   = p_tau_s[0];

    // Per-lane tap value (same expression as reference / R1-R8).
    float ft = (float)lane;
    float v = (lane < KLEN) ? (expf(-ft / tau_m) - expf(-ft / tau_s)) : 0.0f;

    // Reference-ordered sequential sum t = 0..49 (bit-identical order).
    float ksum = 0.0f;
    for (int t = 0; t < KLEN; ++t)
        ksum += __shfl(v, t, 64);
    const float kden = ksum + 1e-10f;
    const float kt = v / kden;

    if (lane < KLEN) wsf[lane] = kt;
    if (lane == 0)   wsf[KLEN] = solve_thresh(p_v_reset[0], p_v_th[0]);
}

// ---------------- K1: conv -> spikes(=cand) + per-chunk flags ----------------
__global__ __launch_bounds__(256)
void conv_kernel(const float* __restrict__ I,
                 const float* __restrict__ wsf,   // taps + athr (uniform loads)
                 float* __restrict__ out,
                 int* __restrict__ flags)
{
    __shared__ __align__(16) float tile[WPB][2][TILEW];

    const int lane  = threadIdx.x & 63;
    const int wid   = threadIdx.x >> 6;
    const int w     = blockIdx.x * WPB + wid;    // 0 .. NROWS*CHK-1
    const int row   = w >> 1;
    const int chunk = w & 1;
    const int gi0   = chunk * GPC;

    // Uniform loads -> SGPRs (no expf/div/binsearch here).
    float kt[KLEN];
#pragma unroll
    for (int t = 0; t < KLEN; ++t) kt[t] = wsf[t];
    const float athr = wsf[KLEN];

    const float* Irow = I + (size_t)row * TLEN;
    float* Orow = out + (size_t)row * TLEN;

    float Cv[4], Nv[4], Lv[4];
    {
        f4 a = *(const f4*)(Irow + (size_t)gi0 * GRP + 4 * lane);
        Cv[0] = a.x; Cv[1] = a.y; Cv[2] = a.z; Cv[3] = a.w;
        f4 c = *(const f4*)(Irow + (size_t)(gi0 + 1) * GRP + 4 * lane);
        Nv[0] = c.x; Nv[1] = c.y; Nv[2] = c.z; Nv[3] = c.w;
    }

    // Prologue tile0: halo-left (zeros for row start, else real data), main.
    if (lane < 8) {
        f4 h;
        if (chunk == 0) h = (f4){0.0f, 0.0f, 0.0f, 0.0f};
        else            h = *(const f4*)(Irow + (size_t)gi0 * GRP - 32 + 4 * lane);
        *(f4*)&tile[wid][0][4 * lane] = h;
    }
    {
        f4 c; c.x = Cv[0]; c.y = Cv[1]; c.z = Cv[2]; c.w = Cv[3];
        *(f4*)&tile[wid][0][32 + 4 * lane] = c;
    }

    int rowflag = 0;

    for (int g = 0; g < GPC; ++g) {
        const int cur = g & 1;
        const int nxt = cur ^ 1;
        const int gi  = gi0 + g;

        // ---- prefetch group gi+2 (real across chunk bound; zeros past row) ----
        if (gi + 2 < NGRP) {
            f4 a = *(const f4*)(Irow + (size_t)(gi + 2) * GRP + 4 * lane);
            Lv[0] = a.x; Lv[1] = a.y; Lv[2] = a.z; Lv[3] = a.w;
        } else {
            Lv[0] = Lv[1] = Lv[2] = Lv[3] = 0.0f;
        }

        // ---- tile maintenance (wave-private LDS, same-wave in-order) ----
        f4 nv; nv.x = Nv[0]; nv.y = Nv[1]; nv.z = Nv[2]; nv.w = Nv[3];
        if (lane < 8)
            *(f4*)&tile[wid][cur][288 + 4 * lane] = nv;
        *(f4*)&tile[wid][nxt][32 + 4 * lane] = nv;
        if (lane >= 56) {
            f4 cv; cv.x = Cv[0]; cv.y = Cv[1]; cv.z = Cv[2]; cv.w = Cv[3];
            *(f4*)&tile[wid][nxt][4 * (lane - 56)] = cv;
        }

        // ---- window read: elems 4l+4 .. 4l+63 ----
        f4 wv[15];
#pragma unroll
        for (int i = 0; i < 15; ++i)
            wv[i] = *(const f4*)&tile[wid][cur][4 * lane + 4 + 4 * i];
#define WIN(m) (wv[(m) >> 2][(m) & 3])

        // ---- convolution: identical order/operands to R6/R7/R8 ----
        float acc[4];
        acc[0] = acc[1] = acc[2] = acc[3] = 0.0f;
#pragma unroll
        for (int o = -25; o <= 27; ++o) {
            const float w2 = WIN(o + 28);
#pragma unroll
            for (int k = 0; k < 4; ++k) {
                const int jj = k + 24 - o;
                if (jj >= 0 && jj < KLEN)
                    acc[k] = fmaf(kt[jj], w2, acc[k]);
            }
        }
#undef WIN

        // ---- candidates -> spikes (refractory repair in K2) ----
        const int tb = gi * GRP + 4 * lane;
        int cand[4];
#pragma unroll
        for (int k = 0; k < 4; ++k)
            cand[k] = (acc[k] >= athr) ? 1 : 0;
        cand[0] &= (tb != 0);   // spikes[0] forced 0

        rowflag |= cand[0] | cand[1] | cand[2] | cand[3];

        f4 o0;
        o0.x = cand[0] ? 1.0f : 0.0f;
        o0.y = cand[1] ? 1.0f : 0.0f;
        o0.z = cand[2] ? 1.0f : 0.0f;
        o0.w = cand[3] ? 1.0f : 0.0f;
        __builtin_nontemporal_store(o0, (f4*)(Orow + tb));

        // ---- rotate ----
#pragma unroll
        for (int j = 0; j < 4; ++j) { Cv[j] = Nv[j]; Nv[j] = Lv[j]; }
    }

    // Deterministic flag write for every chunk (0 or 1).
    const unsigned long long anyb = __ballot(rowflag != 0);
    if (lane == 0) flags[w] = (anyb != 0ULL) ? 1 : 0;
}

// ---------------- K2: repair flagged rows with exact refractory scan ----------------
__global__ __launch_bounds__(256)
void fixup_kernel(const int* __restrict__ flags,
                  float* __restrict__ out)
{
    const int lane = threadIdx.x & 63;
    const int wid  = threadIdx.x >> 6;
    const int row  = blockIdx.x * WPB + wid;

    if ((flags[2 * row] | flags[2 * row + 1]) == 0) return;  // wave-uniform

    float* Orow = out + (size_t)row * TLEN;
    int r0 = 0;

    for (int g = 0; g < NGRP; ++g) {
        f4 o = *(const f4*)(Orow + g * GRP + 4 * lane);
        int cand[4];
        cand[0] = (o.x != 0.0f);
        cand[1] = (o.y != 0.0f);
        cand[2] = (o.z != 0.0f);
        cand[3] = (o.w != 0.0f);

        const int cm = cand[0] | cand[1] | cand[2] | cand[3];
        const unsigned long long anyc = __ballot(cm != 0);
        if (anyc == 0ULL) { r0 = 0; continue; }   // zeros already correct

        int s0 = 0, s1 = 1, s2 = 2, s3 = 3;
#pragma unroll
        for (int k = 0; k < 4; ++k) {
            const int c3 = cand[k] ? 3 : 0;
            s0 = (s0 > 0) ? (s0 - 1) : c3;
            s1 = (s1 > 0) ? (s1 - 1) : c3;
            s2 = (s2 > 0) ? (s2 - 1) : c3;
            s3 = (s3 > 0) ? (s3 - 1) : c3;
        }
        int P = s0 | (s1 << 2) | (s2 << 4) | (s3 << 6);

#pragma unroll
        for (int d = 1; d < 64; d <<= 1) {
            const int prev = __shfl_up(P, d, 64);
            const int comp = map_compose(prev, P);
            P = (lane >= d) ? comp : P;
        }
        const int Pprev = __shfl_up(P, 1, 64);
        const int sin0  = (lane == 0) ? r0 : ((Pprev >> (2 * r0)) & 3);
        const int Pfull = __shfl(P, 63, 64);
        r0 = (Pfull >> (2 * r0)) & 3;

        int s = sin0;
        float sp[4];
#pragma unroll
        for (int k = 0; k < 4; ++k) {
            const int spike = (s == 0) & cand[k];
            sp[k] = spike ? 1.0f : 0.0f;
            s = (s > 0) ? (s - 1) : (cand[k] ? 3 : 0);
        }
        f4 o0; o0.x = sp[0]; o0.y = sp[1]; o0.z = sp[2]; o0.w = sp[3];
        *(f4*)(Orow + g * GRP + 4 * lane) = o0;
    }
}

// ---------------- Fallback: validated R7 single kernel ----------------
__global__ __launch_bounds__(256)
void srm_kernel(const float* __restrict__ I,
                const float* __restrict__ p_tau_m,
                const float* __restrict__ p_tau_s,
                const float* __restrict__ p_v_th,
                const float* __restrict__ p_v_reset,
                float* __restrict__ out)
{
    __shared__ __align__(16) float tile[WPB][2][TILEW];

    const int lane = threadIdx.x & 63;
    const int wid  = threadIdx.x >> 6;
    const int row  = blockIdx.x * WPB + wid;

    const float tau_m   = p_tau_m[0];
    const float tau_s   = p_tau_s[0];
    const float v_th    = p_v_th[0];
    const float v_reset = p_v_reset[0];

    float ku[KLEN];
    float ksum = 0.0f;
#pragma unroll
    for (int t = 0; t < KLEN; ++t) {
        float ft = (float)t;
        float v = expf(-ft / tau_m) - expf(-ft / tau_s);
        ksum += v;
        ku[t] = uniformf(v);
    }
    const float kden = uniformf(ksum + 1e-10f);
    float kt[KLEN];
#pragma unroll
    for (int t = 0; t < KLEN; ++t) kt[t] = uniformf(ku[t] / kden);

    const float athr = uniformf(solve_thresh(v_reset, v_th));

    const float* Irow = I + (size_t)row * TLEN;
    float* Orow = out + (size_t)row * TLEN;

    float Cv[4], Nv[4], Lv[4];
    {
        f4 a = *(const f4*)(Irow + 0 * GRP + 4 * lane);
        Cv[0] = a.x; Cv[1] = a.y; Cv[2] = a.z; Cv[3] = a.w;
        f4 c = *(const f4*)(Irow + 1 * GRP + 4 * lane);
        Nv[0] = c.x; Nv[1] = c.y; Nv[2] = c.z; Nv[3] = c.w;
    }

    if (lane < 8) {
        f4 z = (f4){0.0f, 0.0f, 0.0f, 0.0f};
        *(f4*)&tile[wid][0][4 * lane] = z;
    }
    {
        f4 c; c.x = Cv[0]; c.y = Cv[1]; c.z = Cv[2]; c.w = Cv[3];
        *(f4*)&tile[wid][0][32 + 4 * lane] = c;
    }

    int r0 = 0;

    for (int g = 0; g < NGRP; ++g) {
        const int cur = g & 1;
        const int nxt = cur ^ 1;

        if (g + 2 < NGRP) {
            f4 a = *(const f4*)(Irow + (size_t)(g + 2) * GRP + 4 * lane);
            Lv[0] = a.x; Lv[1] = a.y; Lv[2] = a.z; Lv[3] = a.w;
        } else {
            Lv[0] = Lv[1] = Lv[2] = Lv[3] = 0.0f;
        }

        f4 nv; nv.x = Nv[0]; nv.y = Nv[1]; nv.z = Nv[2]; nv.w = Nv[3];
        if (lane < 8)
            *(f4*)&tile[wid][cur][288 + 4 * lane] = nv;
        *(f4*)&tile[wid][nxt][32 + 4 * lane] = nv;
        if (lane >= 56) {
            f4 cv; cv.x = Cv[0]; cv.y = Cv[1]; cv.z = Cv[2]; cv.w = Cv[3];
            *(f4*)&tile[wid][nxt][4 * (lane - 56)] = cv;
        }

        f4 wv[15];
#pragma unroll
        for (int i = 0; i < 15; ++i)
            wv[i] = *(const f4*)&tile[wid][cur][4 * lane + 4 + 4 * i];
#define WIN(m) (wv[(m) >> 2][(m) & 3])

        float acc[4];
        acc[0] = acc[1] = acc[2] = acc[3] = 0.0f;
#pragma unroll
        for (int o = -25; o <= 27; ++o) {
            const float w = WIN(o + 28);
#pragma unroll
            for (int k = 0; k < 4; ++k) {
                const int jj = k + 24 - o;
                if (jj >= 0 && jj < KLEN)
                    acc[k] = fmaf(kt[jj], w, acc[k]);
            }
        }
#undef WIN

        const int tb = g * GRP + 4 * lane;
        int cand[4];
#pragma unroll
        for (int k = 0; k < 4; ++k)
            cand[k] = (acc[k] >= athr) ? 1 : 0;
        cand[0] &= (tb != 0);

        const int cm = cand[0] | cand[1] | cand[2] | cand[3];
        const unsigned long long anyc = __ballot(cm != 0);

        f4 o0;
        if (anyc == 0ULL) {
            o0 = (f4){0.0f, 0.0f, 0.0f, 0.0f};
            r0 = 0;
        } else {
            int s0 = 0, s1 = 1, s2 = 2, s3 = 3;
#pragma unroll
            for (int k = 0; k < 4; ++k) {
                const int c3 = cand[k] ? 3 : 0;
                s0 = (s0 > 0) ? (s0 - 1) : c3;
                s1 = (s1 > 0) ? (s1 - 1) : c3;
                s2 = (s2 > 0) ? (s2 - 1) : c3;
                s3 = (s3 > 0) ? (s3 - 1) : c3;
            }
            int P = s0 | (s1 << 2) | (s2 << 4) | (s3 << 6);
#pragma unroll
            for (int d = 1; d < 64; d <<= 1) {
                const int prev = __shfl_up(P, d, 64);
                const int comp = map_compose(prev, P);
                P = (lane >= d) ? comp : P;
            }
            const int Pprev = __shfl_up(P, 1, 64);
            const int sin0  = (lane == 0) ? r0 : ((Pprev >> (2 * r0)) & 3);
            const int Pfull = __shfl(P, 63, 64);
            r0 = (Pfull >> (2 * r0)) & 3;

            int s = sin0;
            float sp[4];
#pragma unroll
            for (int k = 0; k < 4; ++k) {
                const int spike = (s == 0) & cand[k];
                sp[k] = spike ? 1.0f : 0.0f;
                s = (s > 0) ? (s - 1) : (cand[k] ? 3 : 0);
            }
            o0.x = sp[0]; o0.y = sp[1]; o0.z = sp[2]; o0.w = sp[3];
        }

        __builtin_nontemporal_store(o0, (f4*)(Orow + tb));

#pragma unroll
        for (int j = 0; j < 4; ++j) { Cv[j] = Nv[j]; Nv[j] = Lv[j]; }
    }
}

extern "C" void kernel_launch(void* const* d_in, const int* in_sizes, int n_in,
                              void* d_out, int out_size, void* d_ws, size_t ws_size,
                              hipStream_t stream) {
    const float* I       = (const float*)d_in[0];
    const float* tau_m   = (const float*)d_in[1];
    const float* tau_s   = (const float*)d_in[2];
    const float* v_th    = (const float*)d_in[3];
    const float* v_reset = (const float*)d_in[4];
    float* out = (float*)d_out;

    if (ws_size >= WS_NEED) {
        float* wsf  = (float*)d_ws;
        int* flags  = (int*)((char*)d_ws + WS_FLAGS_OFF);
        setup_kernel<<<dim3(1), dim3(64), 0, stream>>>(
            tau_m, tau_s, v_th, v_reset, wsf);
        conv_kernel<<<dim3(NROWS * CHK / WPB), dim3(256), 0, stream>>>(
            I, wsf, out, flags);
        fixup_kernel<<<dim3(NROWS / WPB), dim3(256), 0, stream>>>(flags, out);
    } else {
        srm_kernel<<<dim3(NROWS / WPB), dim3(256), 0, stream>>>(
            I, tau_m, tau_s, v_th, v_reset, out);
    }
}

// Round 10
// 181.723 us; speedup vs baseline: 1.1657x; 1.0023x over previous
//
#include <hip/hip_runtime.h>

// SRM neuron: per-row 50-tap 'same' conv -> threshold -> refractory scan.
// B=4096 rows, T=16384.
// R9: hoist per-wave setup (100 expf + 50 IEEE divs + 32-step binary search
//     ~= 30k cycles/wave, 41% of R7's VALU time) into a one-workgroup K0
//     that writes taps+athr to d_ws. Conv waves s_load them.
//   K0: taps (bit-identical, reference-ordered sum) + exact threshold.
//   K1: chunked conv (2 chunks/row, 8192 waves), LDS window tile,
//       spikes := cand, per-chunk flags. No transcendentals.
//   K2: repair flagged rows with the exact transfer-map refractory scan.
// Fallback: validated self-contained R7 kernel if ws too small.

#define TLEN  16384
#define NROWS 4096
#define GRP   256     // elements per group (64 lanes x 4)
#define NGRP  64      // groups per row
#define KLEN  50
#define WPB   4       // waves per 256-thread block
#define TILEW 336     // padded tile stride (floats); 16B-aligned
#define CHK   2       // chunks per row (K1)
#define GPC   (NGRP / CHK)   // 32 groups per chunk

// d_ws layout: float[0..49] taps, float[50] athr, flags int[] at byte 256.
#define WS_FLAGS_OFF 256
#define WS_NEED (WS_FLAGS_OFF + (size_t)NROWS * CHK * sizeof(int))

typedef float f4 __attribute__((ext_vector_type(4)));

__device__ __forceinline__ float uniformf(float x) {
    return __int_as_float(__builtin_amdgcn_readfirstlane(__float_as_int(x)));
}

// compose: r[s] = then[first[s]]  (apply `first`, then `then`)
__device__ __forceinline__ int map_compose(int first, int then) {
    int r = 0;
#pragma unroll
    for (int s = 0; s < 4; ++s) {
        int a = (first >> (2 * s)) & 3;
        int b = (then >> (2 * a)) & 3;
        r |= b << (2 * s);
    }
    return r;
}

// Smallest float a with (v_reset + a/100.0f) >= v_th, via exact-predicate
// binary search over order-mapped float bits. cand == (acc >= athr) EXACTLY.
__device__ float solve_thresh(float v_reset, float v_th) {
    auto tokey = [](float f) {
        unsigned u = __float_as_uint(f);
        return (u & 0x80000000u) ? ~u : (u | 0x80000000u);
    };
    auto fromkey = [](unsigned k) {
        unsigned u = (k & 0x80000000u) ? (k & 0x7FFFFFFFu) : ~k;
        return __uint_as_float(u);
    };
    const float maxf = 3.402823466e38f;
    unsigned lo = tokey(-maxf), hi = tokey(maxf);
    if (!((v_reset + maxf / 100.0f) >= v_th))
        return __uint_as_float(0x7F800000u);  // pred never true -> +inf
    while (lo < hi) {
        unsigned mid = lo + ((hi - lo) >> 1);
        float a = fromkey(mid);
        if ((v_reset + a / 100.0f) >= v_th) hi = mid;
        else lo = mid + 1;
    }
    return fromkey(lo);
}

// ---------------- K0: taps + exact threshold -> d_ws ----------------
__global__ __launch_bounds__(64)
void setup_kernel(const float* __restrict__ p_tau_m,
                  const float* __restrict__ p_tau_s,
                  const float* __restrict__ p_v_th,
                  const float* __restrict__ p_v_reset,
                  float* __restrict__ wsf)
{
    const int lane = threadIdx.x & 63;
    const float tau_m   = p_tau_m[0];
    const float tau_s   = p_tau_s[0];

    // Per-lane tap value (same expression as reference / R1-R8).
    float ft = (float)lane;
    float v = (lane < KLEN) ? (expf(-ft / tau_m) - expf(-ft / tau_s)) : 0.0f;

    // Reference-ordered sequential sum t = 0..49 (bit-identical order).
    float ksum = 0.0f;
    for (int t = 0; t < KLEN; ++t)
        ksum += __shfl(v, t, 64);
    const float kden = ksum + 1e-10f;
    const float kt = v / kden;

    if (lane < KLEN) wsf[lane] = kt;
    if (lane == 0)   wsf[KLEN] = solve_thresh(p_v_reset[0], p_v_th[0]);
}

// ---------------- K1: conv -> spikes(=cand) + per-chunk flags ----------------
__global__ __launch_bounds__(256)
void conv_kernel(const float* __restrict__ I,
                 const float* __restrict__ wsf,   // taps + athr (uniform loads)
                 float* __restrict__ out,
                 int* __restrict__ flags)
{
    __shared__ __align__(16) float tile[WPB][2][TILEW];

    const int lane  = threadIdx.x & 63;
    const int wid   = threadIdx.x >> 6;
    const int w     = blockIdx.x * WPB + wid;    // 0 .. NROWS*CHK-1
    const int row   = w >> 1;
    const int chunk = w & 1;
    const int gi0   = chunk * GPC;

    // Uniform loads -> SGPRs (no expf/div/binsearch here).
    float kt[KLEN];
#pragma unroll
    for (int t = 0; t < KLEN; ++t) kt[t] = wsf[t];
    const float athr = wsf[KLEN];

    const float* Irow = I + (size_t)row * TLEN;
    float* Orow = out + (size_t)row * TLEN;

    float Cv[4], Nv[4], Lv[4];
    {
        f4 a = *(const f4*)(Irow + (size_t)gi0 * GRP + 4 * lane);
        Cv[0] = a.x; Cv[1] = a.y; Cv[2] = a.z; Cv[3] = a.w;
        f4 c = *(const f4*)(Irow + (size_t)(gi0 + 1) * GRP + 4 * lane);
        Nv[0] = c.x; Nv[1] = c.y; Nv[2] = c.z; Nv[3] = c.w;
    }

    // Prologue tile0: halo-left (zeros for row start, else real data), main.
    if (lane < 8) {
        f4 h;
        if (chunk == 0) h = (f4){0.0f, 0.0f, 0.0f, 0.0f};
        else            h = *(const f4*)(Irow + (size_t)gi0 * GRP - 32 + 4 * lane);
        *(f4*)&tile[wid][0][4 * lane] = h;
    }
    {
        f4 c; c.x = Cv[0]; c.y = Cv[1]; c.z = Cv[2]; c.w = Cv[3];
        *(f4*)&tile[wid][0][32 + 4 * lane] = c;
    }

    int rowflag = 0;

    for (int g = 0; g < GPC; ++g) {
        const int cur = g & 1;
        const int nxt = cur ^ 1;
        const int gi  = gi0 + g;

        // ---- prefetch group gi+2 (real across chunk bound; zeros past row) ----
        if (gi + 2 < NGRP) {
            f4 a = *(const f4*)(Irow + (size_t)(gi + 2) * GRP + 4 * lane);
            Lv[0] = a.x; Lv[1] = a.y; Lv[2] = a.z; Lv[3] = a.w;
        } else {
            Lv[0] = Lv[1] = Lv[2] = Lv[3] = 0.0f;
        }

        // ---- tile maintenance (wave-private LDS, same-wave in-order) ----
        f4 nv; nv.x = Nv[0]; nv.y = Nv[1]; nv.z = Nv[2]; nv.w = Nv[3];
        if (lane < 8)
            *(f4*)&tile[wid][cur][288 + 4 * lane] = nv;
        *(f4*)&tile[wid][nxt][32 + 4 * lane] = nv;
        if (lane >= 56) {
            f4 cv; cv.x = Cv[0]; cv.y = Cv[1]; cv.z = Cv[2]; cv.w = Cv[3];
            *(f4*)&tile[wid][nxt][4 * (lane - 56)] = cv;
        }

        // ---- window read: elems 4l+4 .. 4l+63 ----
        f4 wv[15];
#pragma unroll
        for (int i = 0; i < 15; ++i)
            wv[i] = *(const f4*)&tile[wid][cur][4 * lane + 4 + 4 * i];
#define WIN(m) (wv[(m) >> 2][(m) & 3])

        // ---- convolution: identical order/operands to R6/R7/R8 ----
        float acc[4];
        acc[0] = acc[1] = acc[2] = acc[3] = 0.0f;
#pragma unroll
        for (int o = -25; o <= 27; ++o) {
            const float w2 = WIN(o + 28);
#pragma unroll
            for (int k = 0; k < 4; ++k) {
                const int jj = k + 24 - o;
                if (jj >= 0 && jj < KLEN)
                    acc[k] = fmaf(kt[jj], w2, acc[k]);
            }
        }
#undef WIN

        // ---- candidates -> spikes (refractory repair in K2) ----
        const int tb = gi * GRP + 4 * lane;
        int cand[4];
#pragma unroll
        for (int k = 0; k < 4; ++k)
            cand[k] = (acc[k] >= athr) ? 1 : 0;
        cand[0] &= (tb != 0);   // spikes[0] forced 0

        rowflag |= cand[0] | cand[1] | cand[2] | cand[3];

        f4 o0;
        o0.x = cand[0] ? 1.0f : 0.0f;
        o0.y = cand[1] ? 1.0f : 0.0f;
        o0.z = cand[2] ? 1.0f : 0.0f;
        o0.w = cand[3] ? 1.0f : 0.0f;
        __builtin_nontemporal_store(o0, (f4*)(Orow + tb));

        // ---- rotate ----
#pragma unroll
        for (int j = 0; j < 4; ++j) { Cv[j] = Nv[j]; Nv[j] = Lv[j]; }
    }

    // Deterministic flag write for every chunk (0 or 1).
    const unsigned long long anyb = __ballot(rowflag != 0);
    if (lane == 0) flags[w] = (anyb != 0ULL) ? 1 : 0;
}

// ---------------- K2: repair flagged rows with exact refractory scan ----------------
__global__ __launch_bounds__(256)
void fixup_kernel(const int* __restrict__ flags,
                  float* __restrict__ out)
{
    const int lane = threadIdx.x & 63;
    const int wid  = threadIdx.x >> 6;
    const int row  = blockIdx.x * WPB + wid;

    if ((flags[2 * row] | flags[2 * row + 1]) == 0) return;  // wave-uniform

    float* Orow = out + (size_t)row * TLEN;
    int r0 = 0;

    for (int g = 0; g < NGRP; ++g) {
        f4 o = *(const f4*)(Orow + g * GRP + 4 * lane);
        int cand[4];
        cand[0] = (o.x != 0.0f);
        cand[1] = (o.y != 0.0f);
        cand[2] = (o.z != 0.0f);
        cand[3] = (o.w != 0.0f);

        const int cm = cand[0] | cand[1] | cand[2] | cand[3];
        const unsigned long long anyc = __ballot(cm != 0);
        if (anyc == 0ULL) { r0 = 0; continue; }   // zeros already correct

        int s0 = 0, s1 = 1, s2 = 2, s3 = 3;
#pragma unroll
        for (int k = 0; k < 4; ++k) {
            const int c3 = cand[k] ? 3 : 0;
            s0 = (s0 > 0) ? (s0 - 1) : c3;
            s1 = (s1 > 0) ? (s1 - 1) : c3;
            s2 = (s2 > 0) ? (s2 - 1) : c3;
            s3 = (s3 > 0) ? (s3 - 1) : c3;
        }
        int P = s0 | (s1 << 2) | (s2 << 4) | (s3 << 6);

#pragma unroll
        for (int d = 1; d < 64; d <<= 1) {
            const int prev = __shfl_up(P, d, 64);
            const int comp = map_compose(prev, P);
            P = (lane >= d) ? comp : P;
        }
        const int Pprev = __shfl_up(P, 1, 64);
        const int sin0  = (lane == 0) ? r0 : ((Pprev >> (2 * r0)) & 3);
        const int Pfull = __shfl(P, 63, 64);
        r0 = (Pfull >> (2 * r0)) & 3;

        int s = sin0;
        float sp[4];
#pragma unroll
        for (int k = 0; k < 4; ++k) {
            const int spike = (s == 0) & cand[k];
            sp[k] = spike ? 1.0f : 0.0f;
            s = (s > 0) ? (s - 1) : (cand[k] ? 3 : 0);
        }
        f4 o0; o0.x = sp[0]; o0.y = sp[1]; o0.z = sp[2]; o0.w = sp[3];
        *(f4*)(Orow + g * GRP + 4 * lane) = o0;
    }
}

// ---------------- Fallback: validated R7 single kernel ----------------
__global__ __launch_bounds__(256)
void srm_kernel(const float* __restrict__ I,
                const float* __restrict__ p_tau_m,
                const float* __restrict__ p_tau_s,
                const float* __restrict__ p_v_th,
                const float* __restrict__ p_v_reset,
                float* __restrict__ out)
{
    __shared__ __align__(16) float tile[WPB][2][TILEW];

    const int lane = threadIdx.x & 63;
    const int wid  = threadIdx.x >> 6;
    const int row  = blockIdx.x * WPB + wid;

    const float tau_m   = p_tau_m[0];
    const float tau_s   = p_tau_s[0];
    const float v_th    = p_v_th[0];
    const float v_reset = p_v_reset[0];

    float ku[KLEN];
    float ksum = 0.0f;
#pragma unroll
    for (int t = 0; t < KLEN; ++t) {
        float ft = (float)t;
        float v = expf(-ft / tau_m) - expf(-ft / tau_s);
        ksum += v;
        ku[t] = uniformf(v);
    }
    const float kden = uniformf(ksum + 1e-10f);
    float kt[KLEN];
#pragma unroll
    for (int t = 0; t < KLEN; ++t) kt[t] = uniformf(ku[t] / kden);

    const float athr = uniformf(solve_thresh(v_reset, v_th));

    const float* Irow = I + (size_t)row * TLEN;
    float* Orow = out + (size_t)row * TLEN;

    float Cv[4], Nv[4], Lv[4];
    {
        f4 a = *(const f4*)(Irow + 0 * GRP + 4 * lane);
        Cv[0] = a.x; Cv[1] = a.y; Cv[2] = a.z; Cv[3] = a.w;
        f4 c = *(const f4*)(Irow + 1 * GRP + 4 * lane);
        Nv[0] = c.x; Nv[1] = c.y; Nv[2] = c.z; Nv[3] = c.w;
    }

    if (lane < 8) {
        f4 z = (f4){0.0f, 0.0f, 0.0f, 0.0f};
        *(f4*)&tile[wid][0][4 * lane] = z;
    }
    {
        f4 c; c.x = Cv[0]; c.y = Cv[1]; c.z = Cv[2]; c.w = Cv[3];
        *(f4*)&tile[wid][0][32 + 4 * lane] = c;
    }

    int r0 = 0;

    for (int g = 0; g < NGRP; ++g) {
        const int cur = g & 1;
        const int nxt = cur ^ 1;

        if (g + 2 < NGRP) {
            f4 a = *(const f4*)(Irow + (size_t)(g + 2) * GRP + 4 * lane);
            Lv[0] = a.x; Lv[1] = a.y; Lv[2] = a.z; Lv[3] = a.w;
        } else {
            Lv[0] = Lv[1] = Lv[2] = Lv[3] = 0.0f;
        }

        f4 nv; nv.x = Nv[0]; nv.y = Nv[1]; nv.z = Nv[2]; nv.w = Nv[3];
        if (lane < 8)
            *(f4*)&tile[wid][cur][288 + 4 * lane] = nv;
        *(f4*)&tile[wid][nxt][32 + 4 * lane] = nv;
        if (lane >= 56) {
            f4 cv; cv.x = Cv[0]; cv.y = Cv[1]; cv.z = Cv[2]; cv.w = Cv[3];
            *(f4*)&tile[wid][nxt][4 * (lane - 56)] = cv;
        }

        f4 wv[15];
#pragma unroll
        for (int i = 0; i < 15; ++i)
            wv[i] = *(const f4*)&tile[wid][cur][4 * lane + 4 + 4 * i];
#define WIN(m) (wv[(m) >> 2][(m) & 3])

        float acc[4];
        acc[0] = acc[1] = acc[2] = acc[3] = 0.0f;
#pragma unroll
        for (int o = -25; o <= 27; ++o) {
            const float w = WIN(o + 28);
#pragma unroll
            for (int k = 0; k < 4; ++k) {
                const int jj = k + 24 - o;
                if (jj >= 0 && jj < KLEN)
                    acc[k] = fmaf(kt[jj], w, acc[k]);
            }
        }
#undef WIN

        const int tb = g * GRP + 4 * lane;
        int cand[4];
#pragma unroll
        for (int k = 0; k < 4; ++k)
            cand[k] = (acc[k] >= athr) ? 1 : 0;
        cand[0] &= (tb != 0);

        const int cm = cand[0] | cand[1] | cand[2] | cand[3];
        const unsigned long long anyc = __ballot(cm != 0);

        f4 o0;
        if (anyc == 0ULL) {
            o0 = (f4){0.0f, 0.0f, 0.0f, 0.0f};
            r0 = 0;
        } else {
            int s0 = 0, s1 = 1, s2 = 2, s3 = 3;
#pragma unroll
            for (int k = 0; k < 4; ++k) {
                const int c3 = cand[k] ? 3 : 0;
                s0 = (s0 > 0) ? (s0 - 1) : c3;
                s1 = (s1 > 0) ? (s1 - 1) : c3;
                s2 = (s2 > 0) ? (s2 - 1) : c3;
                s3 = (s3 > 0) ? (s3 - 1) : c3;
            }
            int P = s0 | (s1 << 2) | (s2 << 4) | (s3 << 6);
#pragma unroll
            for (int d = 1; d < 64; d <<= 1) {
                const int prev = __shfl_up(P, d, 64);
                const int comp = map_compose(prev, P);
                P = (lane >= d) ? comp : P;
            }
            const int Pprev = __shfl_up(P, 1, 64);
            const int sin0  = (lane == 0) ? r0 : ((Pprev >> (2 * r0)) & 3);
            const int Pfull = __shfl(P, 63, 64);
            r0 = (Pfull >> (2 * r0)) & 3;

            int s = sin0;
            float sp[4];
#pragma unroll
            for (int k = 0; k < 4; ++k) {
                const int spike = (s == 0) & cand[k];
                sp[k] = spike ? 1.0f : 0.0f;
                s = (s > 0) ? (s - 1) : (cand[k] ? 3 : 0);
            }
            o0.x = sp[0]; o0.y = sp[1]; o0.z = sp[2]; o0.w = sp[3];
        }

        __builtin_nontemporal_store(o0, (f4*)(Orow + tb));

#pragma unroll
        for (int j = 0; j < 4; ++j) { Cv[j] = Nv[j]; Nv[j] = Lv[j]; }
    }
}

extern "C" void kernel_launch(void* const* d_in, const int* in_sizes, int n_in,
                              void* d_out, int out_size, void* d_ws, size_t ws_size,
                              hipStream_t stream) {
    const float* I       = (const float*)d_in[0];
    const float* tau_m   = (const float*)d_in[1];
    const float* tau_s   = (const float*)d_in[2];
    const float* v_th    = (const float*)d_in[3];
    const float* v_reset = (const float*)d_in[4];
    float* out = (float*)d_out;

    if (ws_size >= WS_NEED) {
        float* wsf  = (float*)d_ws;
        int* flags  = (int*)((char*)d_ws + WS_FLAGS_OFF);
        setup_kernel<<<dim3(1), dim3(64), 0, stream>>>(
            tau_m, tau_s, v_th, v_reset, wsf);
        conv_kernel<<<dim3(NROWS * CHK / WPB), dim3(256), 0, stream>>>(
            I, wsf, out, flags);
        fixup_kernel<<<dim3(NROWS / WPB), dim3(256), 0, stream>>>(flags, out);
    } else {
        srm_kernel<<<dim3(NROWS / WPB), dim3(256), 0, stream>>>(
            I, tau_m, tau_s, v_th, v_reset, out);
    }
}